// Round 4
// baseline (636.059 us; speedup 1.0000x reference)
//
#include <hip/hip_runtime.h>
#include <stdint.h>

#define B_   16
#define L_   2048
#define D_   256
#define NROW (B_*L_)

#define EPAD 40    // Es row stride (shorts)
#define TPAD 66    // qkv transpose buffer row stride

typedef __attribute__((ext_vector_type(8))) short s8v;   // 8 x bf16 (as shorts)
typedef __attribute__((ext_vector_type(4))) float f4v;   // MFMA accumulator

__device__ __forceinline__ unsigned short f2b(float f) {   // RNE f32->bf16
    unsigned u = __builtin_bit_cast(unsigned, f);
    return (unsigned short)((u + 0x7fffu + ((u >> 16) & 1u)) >> 16);
}

// async global->LDS, 16B per lane; LDS dest = wave-uniform base + lane*16
__device__ __forceinline__ void gl16(const void* g, void* l) {
    __builtin_amdgcn_global_load_lds(
        (const __attribute__((address_space(1))) unsigned int*)g,
        (__attribute__((address_space(3))) unsigned int*)l, 16, 0, 0);
}

// ---------------- K1: QKV projection ----------------
// grid (512 row-blocks, 2 types), block 256 (4 waves).
// type0: Q from x.  type1: K and V from y (y staged once).
// Xs/Ws reads XOR-swizzled in 16B chunks to kill pow2-stride bank conflicts.
__global__ __launch_bounds__(256) void qkv_kernel(
    const float* __restrict__ x, const float* __restrict__ y,
    const float* __restrict__ Wq, const float* __restrict__ Wk, const float* __restrict__ Wv,
    unsigned short* __restrict__ Qb, unsigned short* __restrict__ Kb,
    unsigned short* __restrict__ Vt,
    float* __restrict__ qn, float* __restrict__ kn)
{
    __shared__ unsigned short Xs[64*256];    // 32 KB input tile (bf16)
    __shared__ unsigned short Ws[64*256];    // 32 KB weight tile (bf16)
    __shared__ unsigned short Ts[64*TPAD];   // V transpose buffer

    const int t    = threadIdx.x;
    const int r0   = blockIdx.x * 64;   // global row (flat b*L + pos)
    const int type = blockIdx.y;        // 0=Q  1=K+V

    const float* X = type ? y : x;

    // Stage X tile [64][256] fp32 -> bf16 LDS, 16B-chunk swizzled by row&15.
    #pragma unroll
    for (int p = 0; p < 16; ++p) {
        int idx  = p*256 + t;
        int row  = idx >> 6;
        int half = idx & 1;              // which 8B half of the 16B chunk
        int blk  = (idx & 63) >> 1;      // 16B chunk index 0..31
        int c4   = blk*8 + half*4;       // source column (shorts/floats)
        float4 vx = *(const float4*)(X + (size_t)(r0+row)*D_ + c4);
        uint2 px;
        px.x = (unsigned)f2b(vx.x) | ((unsigned)f2b(vx.y) << 16);
        px.y = (unsigned)f2b(vx.z) | ((unsigned)f2b(vx.w) << 16);
        *(uint2*)(Xs + row*256 + (blk ^ (row & 15))*8 + half*4) = px;
    }

    const int w = t >> 6, lane = t & 63, q16 = lane & 15, quad = lane >> 4;
    const int m0 = w * 16;   // wave's 16-row band

    float p4[4] = {0.f, 0.f, 0.f, 0.f};   // row-norm partials (Q/K)
    const f4v z4 = {0.f, 0.f, 0.f, 0.f};

    for (int ct = 0; ct < 4; ++ct) {
        const int e0 = ct * 64;

        // ---- Q (type0) or K (type1) weight tile ----
        __syncthreads();   // previous tile's readers done (covers Xs stage on ct=0)
        {
            const float* W = type ? Wk : Wq;
            #pragma unroll
            for (int p = 0; p < 16; ++p) {
                int idx  = p*256 + t;
                int row  = idx >> 6;
                int half = idx & 1;
                int blk  = (idx & 63) >> 1;
                int c4   = blk*8 + half*4;
                float4 vw = *(const float4*)(W + (size_t)(e0+row)*D_ + c4);
                uint2 pw;
                pw.x = (unsigned)f2b(vw.x) | ((unsigned)f2b(vw.y) << 16);
                pw.y = (unsigned)f2b(vw.z) | ((unsigned)f2b(vw.w) << 16);
                *(uint2*)(Ws + row*256 + (blk ^ (row & 15))*8 + half*4) = pw;
            }
        }
        __syncthreads();

        f4v acc[4];
        #pragma unroll
        for (int n = 0; n < 4; ++n) acc[n] = z4;
        #pragma unroll
        for (int c = 0; c < 8; ++c) {
            s8v a = *(const s8v*)(Xs + (m0 + q16)*256 + (((c*4+quad) ^ q16)*8));
            #pragma unroll
            for (int n = 0; n < 4; ++n) {
                s8v bb = *(const s8v*)(Ws + (n*16 + q16)*256 + (((c*4+quad) ^ q16)*8));
                acc[n] = __builtin_amdgcn_mfma_f32_16x16x32_bf16(a, bb, acc[n], 0, 0, 0);
            }
        }
        {
            unsigned short* Out = type ? Kb : Qb;
            // C-layout: value at (row = quad*4+r, col = n*16+q16)
            #pragma unroll
            for (int n = 0; n < 4; ++n)
                #pragma unroll
                for (int r = 0; r < 4; ++r) {
                    float v = acc[n][r];
                    p4[r] += v * v;
                    Out[(size_t)(r0 + m0 + quad*4 + r)*D_ + e0 + n*16 + q16] = f2b(v);
                }
        }

        if (type) {
            // ---- V weight tile ----
            __syncthreads();   // K-mfma readers of Ws done
            #pragma unroll
            for (int p = 0; p < 16; ++p) {
                int idx  = p*256 + t;
                int row  = idx >> 6;
                int half = idx & 1;
                int blk  = (idx & 63) >> 1;
                int c4   = blk*8 + half*4;
                float4 vw = *(const float4*)(Wv + (size_t)(e0+row)*D_ + c4);
                uint2 pw;
                pw.x = (unsigned)f2b(vw.x) | ((unsigned)f2b(vw.y) << 16);
                pw.y = (unsigned)f2b(vw.z) | ((unsigned)f2b(vw.w) << 16);
                *(uint2*)(Ws + row*256 + (blk ^ (row & 15))*8 + half*4) = pw;
            }
            __syncthreads();

            f4v vacc[4];
            #pragma unroll
            for (int n = 0; n < 4; ++n) vacc[n] = z4;
            #pragma unroll
            for (int c = 0; c < 8; ++c) {
                s8v a = *(const s8v*)(Xs + (m0 + q16)*256 + (((c*4+quad) ^ q16)*8));
                #pragma unroll
                for (int n = 0; n < 4; ++n) {
                    s8v bb = *(const s8v*)(Ws + (n*16 + q16)*256 + (((c*4+quad) ^ q16)*8));
                    vacc[n] = __builtin_amdgcn_mfma_f32_16x16x32_bf16(a, bb, vacc[n], 0, 0, 0);
                }
            }
            // transpose via LDS, write Vt[b][d][k] coalesced
            #pragma unroll
            for (int n = 0; n < 4; ++n)
                #pragma unroll
                for (int r = 0; r < 4; ++r)
                    Ts[(m0 + quad*4 + r)*TPAD + n*16 + q16] = f2b(vacc[n][r]);
            __syncthreads();
            int j    = t >> 2;   // local d col 0..63
            int kseg = t & 3;    // 16 k's each
            unsigned pk[8];
            #pragma unroll
            for (int i = 0; i < 8; ++i) {
                unsigned lo = Ts[(kseg*16 + 2*i    )*TPAD + j];
                unsigned hi = Ts[(kseg*16 + 2*i + 1)*TPAD + j];
                pk[i] = lo | (hi << 16);
            }
            int bb_ = r0 >> 11;         // batch index
            int k0g = r0 & (L_ - 1);    // k offset within batch
            unsigned short* dst = Vt + (size_t)(bb_*D_ + e0 + j)*L_ + k0g + kseg*16;
            *(uint4*)dst       = make_uint4(pk[0], pk[1], pk[2], pk[3]);
            *((uint4*)dst + 1) = make_uint4(pk[4], pk[5], pk[6], pk[7]);
        }
    }

    {
        float* norm = type ? kn : qn;
        #pragma unroll
        for (int r = 0; r < 4; ++r) {
            float v = p4[r];
            v += __shfl_xor(v, 1, 16);
            v += __shfl_xor(v, 2, 16);
            v += __shfl_xor(v, 4, 16);
            v += __shfl_xor(v, 8, 16);
            if (q16 == 0) norm[r0 + m0 + quad*4 + r] = v;
        }
    }
}

// ---- shared staging helpers (DMA direct to LDS, XOR-swizzled global src) ----
// Ks: 32 rows x 256 cols bf16; 16B chunk blk stored at global blk^(row&15)
__device__ __forceinline__ void stage_K(const unsigned short* Kb, unsigned short* ks,
                                        int bk, int k0, int w, int lane) {
    #pragma unroll
    for (int p = 0; p < 4; ++p) {
        int slot = p*256 + w*64 + lane;
        int row  = slot >> 5;
        int blk  = slot & 31;
        gl16(Kb + (size_t)(bk + k0 + row)*D_ + ((blk ^ (row & 15))*8),
             ks + (size_t)(p*256 + w*64)*8);
    }
}
// Vs: 256 rows(d) x 32 cols(k) bf16; chunk blk (0..3) swizzled by (d>>1)&3
__device__ __forceinline__ void stage_V(const unsigned short* Vt, unsigned short* vs,
                                        int bD, int k0, int w, int lane) {
    #pragma unroll
    for (int p = 0; p < 4; ++p) {
        int slot = p*256 + w*64 + lane;
        int d    = slot >> 2;
        int blk  = slot & 3;
        gl16(Vt + (size_t)(bD + d)*L_ + k0 + ((blk ^ ((d >> 1) & 3))*8),
             vs + (size_t)(p*256 + w*64)*8);
    }
}

// ---------------- K2a: rowsum + O = E @ V (unnormalized E) ----------------
// grid (32 qb, 16 b) = 512 blocks (2/CU, 8 waves/CU), wave owns 16 q rows.
// Single-barrier double-buffered DMA loop. No global stores inside the loop
// (barrier drain = DMAs only). Epilogue: rowsum written, O scaled by 1/rs.
__global__ __launch_bounds__(256) void attnpv_kernel(
    const unsigned short* __restrict__ Qb, const unsigned short* __restrict__ Kb,
    const unsigned short* __restrict__ Vt,
    const float* __restrict__ qn, const float* __restrict__ kn,
    const unsigned char* __restrict__ mask,
    float* __restrict__ rowsum, float* __restrict__ att_out)
{
    __shared__ unsigned short Ks[2][32*256];    // 16 KB each
    __shared__ unsigned short Vs[2][256*32];    // 16 KB each
    __shared__ unsigned short Es[4][16*EPAD];   // per-wave E tile (5 KB)

    const int t  = threadIdx.x;
    const int q0 = blockIdx.x * 64;
    const int b  = blockIdx.y;
    const int bk = b * L_;
    const int bD = b * D_;
    const int w = t >> 6, lane = t & 63, q16 = lane & 15, quad = lane >> 4;

    const int qrow = bk + q0 + w*16;
    s8v qa[8];
    float qnr[4];
    #pragma unroll
    for (int c = 0; c < 8; ++c)
        qa[c] = *(const s8v*)(Qb + (size_t)(qrow + q16)*D_ + c*32 + quad*8);
    #pragma unroll
    for (int r = 0; r < 4; ++r)
        qnr[r] = qn[qrow + quad*4 + r];

    float rs[4] = {0.f, 0.f, 0.f, 0.f};
    const f4v z4 = {0.f, 0.f, 0.f, 0.f};
    f4v O[16];
    #pragma unroll
    for (int n = 0; n < 16; ++n) O[n] = z4;

    stage_K(Kb, Ks[0], bk, 0, w, lane);
    stage_V(Vt, Vs[0], bD, 0, w, lane);
    for (int kt = 0; kt < 64; ++kt) {
        const int k0 = kt * 32;
        const int cur = kt & 1;
        __syncthreads();                       // Ks/Vs[cur] ready; prev bufs free
        if (kt < 63) {
            stage_K(Kb, Ks[cur ^ 1], bk, k0 + 32, w, lane);
            stage_V(Vt, Vs[cur ^ 1], bD, k0 + 32, w, lane);
        }

        float kcv[2]; int mkv[2];
        #pragma unroll
        for (int n = 0; n < 2; ++n) {
            kcv[n] = kn[bk + k0 + n*16 + q16];
            mkv[n] = mask[bk + k0 + n*16 + q16];
        }

        #pragma unroll
        for (int n = 0; n < 2; ++n) {
            f4v s = {0.f, 0.f, 0.f, 0.f};
            #pragma unroll
            for (int c = 0; c < 8; ++c) {
                s8v bb = *(const s8v*)(Ks[cur] + (n*16 + q16)*256 + (((c*4+quad) ^ q16)*8));
                s = __builtin_amdgcn_mfma_f32_16x16x32_bf16(qa[c], bb, s, 0, 0, 0);
            }
            #pragma unroll
            for (int r = 0; r < 4; ++r) {
                float d2 = qnr[r] + kcv[n] - 2.0f * s[r];
                float dist = sqrtf(fmaxf(d2, 0.f));
                float E = mkv[n] ? 0.f : __expf(__expf(-dist));
                rs[r] += E;
                Es[w][(quad*4 + r)*EPAD + n*16 + q16] =
                    (unsigned short)(__builtin_bit_cast(unsigned, E) >> 16);
            }
        }
        // PV: A = own-wave Es (same-wave write->read, lgkmcnt ordered)
        s8v af = *(const s8v*)(&Es[w][q16*EPAD + quad*8]);
        #pragma unroll
        for (int n = 0; n < 16; ++n) {
            s8v vb = *(const s8v*)(Vs[cur] + (n*16 + q16)*32 +
                                   ((quad ^ ((q16 >> 1) & 3))*8));
            O[n] = __builtin_amdgcn_mfma_f32_16x16x32_bf16(af, vb, O[n], 0, 0, 0);
        }
    }

    // rowsum (complete: block covered all k) + inv; butterfly leaves sum in all lanes
    float inv[4];
    #pragma unroll
    for (int r = 0; r < 4; ++r) {
        float v = rs[r];
        v += __shfl_xor(v, 1, 16);
        v += __shfl_xor(v, 2, 16);
        v += __shfl_xor(v, 4, 16);
        v += __shfl_xor(v, 8, 16);
        if (q16 == 0) rowsum[qrow + quad*4 + r] = v;
        inv[r] = 1.0f / v;
    }

    #pragma unroll
    for (int n = 0; n < 16; ++n)
        #pragma unroll
        for (int r = 0; r < 4; ++r)
            att_out[(size_t)(qrow + quad*4 + r)*D_ + n*16 + q16] = O[n][r] * inv[r];
}

// ---------------- K2b: attn = E * inv (write-only pass) ----------------
// grid (32 qb, 16 b, 2 kslice) = 1024 blocks (4+/CU). K staging only; no V,
// no Es, no PV. Write-BW bound by design.
__global__ __launch_bounds__(256) void attnw_kernel(
    const unsigned short* __restrict__ Qb, const unsigned short* __restrict__ Kb,
    const float* __restrict__ qn, const float* __restrict__ kn,
    const float* __restrict__ rowsum,
    const unsigned char* __restrict__ mask,
    float* __restrict__ attn_out)
{
    __shared__ unsigned short Ks[2][32*256];   // 16 KB each

    const int t  = threadIdx.x;
    const int q0 = blockIdx.x * 64;
    const int b  = blockIdx.y;
    const int bk = b * L_;
    const int kbase = blockIdx.z * 1024;
    const int w = t >> 6, lane = t & 63, q16 = lane & 15, quad = lane >> 4;

    const int qrow = bk + q0 + w*16;
    s8v qa[8];
    float qnr[4], inv[4];
    #pragma unroll
    for (int c = 0; c < 8; ++c)
        qa[c] = *(const s8v*)(Qb + (size_t)(qrow + q16)*D_ + c*32 + quad*8);
    #pragma unroll
    for (int r = 0; r < 4; ++r) {
        qnr[r] = qn[qrow + quad*4 + r];
        inv[r] = 1.0f / rowsum[qrow + quad*4 + r];
    }

    stage_K(Kb, Ks[0], bk, kbase, w, lane);
    for (int kt = 0; kt < 32; ++kt) {
        const int k0 = kbase + kt*32;
        const int cur = kt & 1;
        __syncthreads();                       // drains own DMAs -> Ks[cur] ready
        if (kt < 31) stage_K(Kb, Ks[cur ^ 1], bk, k0 + 32, w, lane);

        float kcv[2]; int mkv[2];
        #pragma unroll
        for (int n = 0; n < 2; ++n) {
            kcv[n] = kn[bk + k0 + n*16 + q16];
            mkv[n] = mask[bk + k0 + n*16 + q16];
        }
        #pragma unroll
        for (int n = 0; n < 2; ++n) {
            f4v s = {0.f, 0.f, 0.f, 0.f};
            #pragma unroll
            for (int c = 0; c < 8; ++c) {
                s8v bb = *(const s8v*)(Ks[cur] + (n*16 + q16)*256 + (((c*4+quad) ^ q16)*8));
                s = __builtin_amdgcn_mfma_f32_16x16x32_bf16(qa[c], bb, s, 0, 0, 0);
            }
            #pragma unroll
            for (int r = 0; r < 4; ++r) {
                float d2 = qnr[r] + kcv[n] - 2.0f * s[r];
                float dist = sqrtf(fmaxf(d2, 0.f));
                float E = mkv[n] ? 0.f : __expf(__expf(-dist));
                attn_out[(size_t)(qrow + quad*4 + r)*L_ + k0 + n*16 + q16] = E * inv[r];
            }
        }
    }
}

extern "C" void kernel_launch(void* const* d_in, const int* in_sizes, int n_in,
                              void* d_out, int out_size, void* d_ws, size_t ws_size,
                              hipStream_t stream) {
    (void)in_sizes; (void)n_in; (void)out_size; (void)ws_size;
    const float* x  = (const float*)d_in[0];
    const float* y  = (const float*)d_in[1];
    const unsigned char* mask = (const unsigned char*)d_in[2];
    const float* Wq = (const float*)d_in[3];
    const float* Wk = (const float*)d_in[4];
    const float* Wv = (const float*)d_in[5];

    // ws: Qb | Kb | Vt (bf16, 16.78 MB each) | qn | kn | rowsum (fp32)
    char* ws = (char*)d_ws;
    unsigned short* Qb = (unsigned short*)ws;
    unsigned short* Kb = Qb + (size_t)NROW * D_;
    unsigned short* Vt = Kb + (size_t)NROW * D_;
    float* qn     = (float*)(ws + 3 * (size_t)NROW * D_ * 2);
    float* kn     = qn + NROW;
    float* rowsum = kn + NROW;

    float* att_out = (float*)d_out;                       // [B, LQ, D]
    float* attn    = att_out + (size_t)NROW * D_;         // [B, LQ, LK]

    qkv_kernel<<<dim3(512, 2), 256, 0, stream>>>(x, y, Wq, Wk, Wv,
                                                 Qb, Kb, Vt, qn, kn);
    attnpv_kernel<<<dim3(32, 16), 256, 0, stream>>>(Qb, Kb, Vt, qn, kn, mask,
                                                    rowsum, att_out);
    attnw_kernel<<<dim3(32, 16, 2), 256, 0, stream>>>(Qb, Kb, qn, kn, rowsum,
                                                      mask, attn);
}

// Round 5
// 590.718 us; speedup vs baseline: 1.0768x; 1.0768x over previous
//
#include <hip/hip_runtime.h>
#include <stdint.h>

#define B_   16
#define L_   2048
#define D_   256
#define NROW (B_*L_)

#define EPAD 40    // Es row stride (shorts)
#define TPAD 66    // qkv transpose buffer row stride

typedef __attribute__((ext_vector_type(8))) short s8v;   // 8 x bf16 (as shorts)
typedef __attribute__((ext_vector_type(4))) float f4v;   // MFMA accumulator

__device__ __forceinline__ unsigned short f2b(float f) {   // RNE f32->bf16
    unsigned u = __builtin_bit_cast(unsigned, f);
    return (unsigned short)((u + 0x7fffu + ((u >> 16) & 1u)) >> 16);
}

// async global->LDS, 16B per lane; LDS dest = wave-uniform base + lane*16
__device__ __forceinline__ void gl16(const void* g, void* l) {
    __builtin_amdgcn_global_load_lds(
        (const __attribute__((address_space(1))) unsigned int*)g,
        (__attribute__((address_space(3))) unsigned int*)l, 16, 0, 0);
}

// ---------------- K1: QKV projection ----------------
// grid (512 row-blocks, 2 types), block 256 (4 waves).
// type0: Q from x.  type1: K and V from y (y staged once).
// Xs/Ws reads XOR-swizzled in 16B chunks to kill pow2-stride bank conflicts.
__global__ __launch_bounds__(256) void qkv_kernel(
    const float* __restrict__ x, const float* __restrict__ y,
    const float* __restrict__ Wq, const float* __restrict__ Wk, const float* __restrict__ Wv,
    unsigned short* __restrict__ Qb, unsigned short* __restrict__ Kb,
    unsigned short* __restrict__ Vt,
    float* __restrict__ qn, float* __restrict__ kn)
{
    __shared__ unsigned short Xs[64*256];    // 32 KB input tile (bf16)
    __shared__ unsigned short Ws[64*256];    // 32 KB weight tile (bf16)
    __shared__ unsigned short Ts[64*TPAD];   // V transpose buffer

    const int t    = threadIdx.x;
    const int r0   = blockIdx.x * 64;   // global row (flat b*L + pos)
    const int type = blockIdx.y;        // 0=Q  1=K+V

    const float* X = type ? y : x;

    // Stage X tile [64][256] fp32 -> bf16 LDS, 16B-chunk swizzled by row&15.
    #pragma unroll
    for (int p = 0; p < 16; ++p) {
        int idx  = p*256 + t;
        int row  = idx >> 6;
        int half = idx & 1;              // which 8B half of the 16B chunk
        int blk  = (idx & 63) >> 1;      // 16B chunk index 0..31
        int c4   = blk*8 + half*4;       // source column (shorts/floats)
        float4 vx = *(const float4*)(X + (size_t)(r0+row)*D_ + c4);
        uint2 px;
        px.x = (unsigned)f2b(vx.x) | ((unsigned)f2b(vx.y) << 16);
        px.y = (unsigned)f2b(vx.z) | ((unsigned)f2b(vx.w) << 16);
        *(uint2*)(Xs + row*256 + (blk ^ (row & 15))*8 + half*4) = px;
    }

    const int w = t >> 6, lane = t & 63, q16 = lane & 15, quad = lane >> 4;
    const int m0 = w * 16;   // wave's 16-row band

    float p4[4] = {0.f, 0.f, 0.f, 0.f};   // row-norm partials (Q/K)
    const f4v z4 = {0.f, 0.f, 0.f, 0.f};

    for (int ct = 0; ct < 4; ++ct) {
        const int e0 = ct * 64;

        // ---- Q (type0) or K (type1) weight tile ----
        __syncthreads();   // previous tile's readers done (covers Xs stage on ct=0)
        {
            const float* W = type ? Wk : Wq;
            #pragma unroll
            for (int p = 0; p < 16; ++p) {
                int idx  = p*256 + t;
                int row  = idx >> 6;
                int half = idx & 1;
                int blk  = (idx & 63) >> 1;
                int c4   = blk*8 + half*4;
                float4 vw = *(const float4*)(W + (size_t)(e0+row)*D_ + c4);
                uint2 pw;
                pw.x = (unsigned)f2b(vw.x) | ((unsigned)f2b(vw.y) << 16);
                pw.y = (unsigned)f2b(vw.z) | ((unsigned)f2b(vw.w) << 16);
                *(uint2*)(Ws + row*256 + (blk ^ (row & 15))*8 + half*4) = pw;
            }
        }
        __syncthreads();

        f4v acc[4];
        #pragma unroll
        for (int n = 0; n < 4; ++n) acc[n] = z4;
        #pragma unroll
        for (int c = 0; c < 8; ++c) {
            s8v a = *(const s8v*)(Xs + (m0 + q16)*256 + (((c*4+quad) ^ q16)*8));
            #pragma unroll
            for (int n = 0; n < 4; ++n) {
                s8v bb = *(const s8v*)(Ws + (n*16 + q16)*256 + (((c*4+quad) ^ q16)*8));
                acc[n] = __builtin_amdgcn_mfma_f32_16x16x32_bf16(a, bb, acc[n], 0, 0, 0);
            }
        }
        {
            unsigned short* Out = type ? Kb : Qb;
            // C-layout: value at (row = quad*4+r, col = n*16+q16)
            #pragma unroll
            for (int n = 0; n < 4; ++n)
                #pragma unroll
                for (int r = 0; r < 4; ++r) {
                    float v = acc[n][r];
                    p4[r] += v * v;
                    Out[(size_t)(r0 + m0 + quad*4 + r)*D_ + e0 + n*16 + q16] = f2b(v);
                }
        }

        if (type) {
            // ---- V weight tile ----
            __syncthreads();   // K-mfma readers of Ws done
            #pragma unroll
            for (int p = 0; p < 16; ++p) {
                int idx  = p*256 + t;
                int row  = idx >> 6;
                int half = idx & 1;
                int blk  = (idx & 63) >> 1;
                int c4   = blk*8 + half*4;
                float4 vw = *(const float4*)(Wv + (size_t)(e0+row)*D_ + c4);
                uint2 pw;
                pw.x = (unsigned)f2b(vw.x) | ((unsigned)f2b(vw.y) << 16);
                pw.y = (unsigned)f2b(vw.z) | ((unsigned)f2b(vw.w) << 16);
                *(uint2*)(Ws + row*256 + (blk ^ (row & 15))*8 + half*4) = pw;
            }
            __syncthreads();

            f4v vacc[4];
            #pragma unroll
            for (int n = 0; n < 4; ++n) vacc[n] = z4;
            #pragma unroll
            for (int c = 0; c < 8; ++c) {
                s8v a = *(const s8v*)(Xs + (m0 + q16)*256 + (((c*4+quad) ^ q16)*8));
                #pragma unroll
                for (int n = 0; n < 4; ++n) {
                    s8v bb = *(const s8v*)(Ws + (n*16 + q16)*256 + (((c*4+quad) ^ q16)*8));
                    vacc[n] = __builtin_amdgcn_mfma_f32_16x16x32_bf16(a, bb, vacc[n], 0, 0, 0);
                }
            }
            // transpose via LDS, write Vt[b][d][k] coalesced
            #pragma unroll
            for (int n = 0; n < 4; ++n)
                #pragma unroll
                for (int r = 0; r < 4; ++r)
                    Ts[(m0 + quad*4 + r)*TPAD + n*16 + q16] = f2b(vacc[n][r]);
            __syncthreads();
            int j    = t >> 2;   // local d col 0..63
            int kseg = t & 3;    // 16 k's each
            unsigned pk[8];
            #pragma unroll
            for (int i = 0; i < 8; ++i) {
                unsigned lo = Ts[(kseg*16 + 2*i    )*TPAD + j];
                unsigned hi = Ts[(kseg*16 + 2*i + 1)*TPAD + j];
                pk[i] = lo | (hi << 16);
            }
            int bb_ = r0 >> 11;         // batch index
            int k0g = r0 & (L_ - 1);    // k offset within batch
            unsigned short* dst = Vt + (size_t)(bb_*D_ + e0 + j)*L_ + k0g + kseg*16;
            *(uint4*)dst       = make_uint4(pk[0], pk[1], pk[2], pk[3]);
            *((uint4*)dst + 1) = make_uint4(pk[4], pk[5], pk[6], pk[7]);
        }
    }

    {
        float* norm = type ? kn : qn;
        #pragma unroll
        for (int r = 0; r < 4; ++r) {
            float v = p4[r];
            v += __shfl_xor(v, 1, 16);
            v += __shfl_xor(v, 2, 16);
            v += __shfl_xor(v, 4, 16);
            v += __shfl_xor(v, 8, 16);
            if (q16 == 0) norm[r0 + m0 + quad*4 + r] = v;
        }
    }
}

// ---- staging helpers (DMA direct to LDS, XOR-swizzled global src) ----
// Ks: 32 rows x 256 cols bf16; 16B chunk blk stored at global blk^(row&15)
__device__ __forceinline__ void stage_K(const unsigned short* Kb, unsigned short* ks,
                                        int bk, int k0, int w, int lane) {
    #pragma unroll
    for (int p = 0; p < 4; ++p) {
        int slot = p*256 + w*64 + lane;
        int row  = slot >> 5;
        int blk  = slot & 31;
        gl16(Kb + (size_t)(bk + k0 + row)*D_ + ((blk ^ (row & 15))*8),
             ks + (size_t)(p*256 + w*64)*8);
    }
}
// Vs: 256 rows(d) x 32 cols(k) bf16; chunk blk (0..3) swizzled by (d>>1)&3
__device__ __forceinline__ void stage_V(const unsigned short* Vt, unsigned short* vs,
                                        int bD, int k0, int w, int lane) {
    #pragma unroll
    for (int p = 0; p < 4; ++p) {
        int slot = p*256 + w*64 + lane;
        int d    = slot >> 2;
        int blk  = slot & 3;
        gl16(Vt + (size_t)(bD + d)*L_ + k0 + ((blk ^ ((d >> 1) & 3))*8),
             vs + (size_t)(p*256 + w*64)*8);
    }
}

// -------- K2: single transcendental pass --------
// grid (32 qb, 16 b) = 512 blocks (2/CU, 8 waves/CU), wave owns 16 q rows.
// Per k-tile: QK MFMA -> E = exp(exp(-dist)) (once!) -> rowsum (regs) ->
// Es LDS roundtrip -> PV MFMA -> stream E bf16 (row-major) to global.
// Epilogue: rowsum + att_out (scaled by 1/rs).
__global__ __launch_bounds__(256) void attnpv_kernel(
    const unsigned short* __restrict__ Qb, const unsigned short* __restrict__ Kb,
    const unsigned short* __restrict__ Vt,
    const float* __restrict__ qn, const float* __restrict__ kn,
    const unsigned char* __restrict__ mask,
    unsigned short* __restrict__ Eb,
    float* __restrict__ rowsum, float* __restrict__ att_out)
{
    __shared__ unsigned short Ks[2][32*256];    // 16 KB each
    __shared__ unsigned short Vs[2][256*32];    // 16 KB each
    __shared__ unsigned short Es[4][16*EPAD];   // per-wave E tile (5 KB)

    const int t  = threadIdx.x;
    const int q0 = blockIdx.x * 64;
    const int b  = blockIdx.y;
    const int bk = b * L_;
    const int bD = b * D_;
    const int w = t >> 6, lane = t & 63, q16 = lane & 15, quad = lane >> 4;

    const int qrow = bk + q0 + w*16;
    s8v qa[8];
    float qnr[4];
    #pragma unroll
    for (int c = 0; c < 8; ++c)
        qa[c] = *(const s8v*)(Qb + (size_t)(qrow + q16)*D_ + c*32 + quad*8);
    #pragma unroll
    for (int r = 0; r < 4; ++r)
        qnr[r] = qn[qrow + quad*4 + r];

    // E-export addressing: lane -> (row = lane>>2, colseg = lane&3)
    unsigned short* ebase = Eb + (size_t)(qrow + (lane >> 2))*L_ + (lane & 3)*8;
    const unsigned short* esrc = &Es[w][(lane >> 2)*EPAD + (lane & 3)*8];

    float rs[4] = {0.f, 0.f, 0.f, 0.f};
    const f4v z4 = {0.f, 0.f, 0.f, 0.f};
    f4v O[16];
    #pragma unroll
    for (int n = 0; n < 16; ++n) O[n] = z4;

    stage_K(Kb, Ks[0], bk, 0, w, lane);
    stage_V(Vt, Vs[0], bD, 0, w, lane);
    for (int kt = 0; kt < 64; ++kt) {
        const int k0 = kt * 32;
        const int cur = kt & 1;
        __syncthreads();                       // Ks/Vs[cur] ready; prev bufs free
        if (kt < 63) {
            stage_K(Kb, Ks[cur ^ 1], bk, k0 + 32, w, lane);
            stage_V(Vt, Vs[cur ^ 1], bD, k0 + 32, w, lane);
        }

        float kcv[2]; int mkv[2];
        #pragma unroll
        for (int n = 0; n < 2; ++n) {
            kcv[n] = kn[bk + k0 + n*16 + q16];
            mkv[n] = mask[bk + k0 + n*16 + q16];
        }

        #pragma unroll
        for (int n = 0; n < 2; ++n) {
            f4v s = {0.f, 0.f, 0.f, 0.f};
            #pragma unroll
            for (int c = 0; c < 8; ++c) {
                s8v bb = *(const s8v*)(Ks[cur] + (n*16 + q16)*256 + (((c*4+quad) ^ q16)*8));
                s = __builtin_amdgcn_mfma_f32_16x16x32_bf16(qa[c], bb, s, 0, 0, 0);
            }
            #pragma unroll
            for (int r = 0; r < 4; ++r) {
                float d2 = qnr[r] + kcv[n] - 2.0f * s[r];
                float dist = sqrtf(fmaxf(d2, 0.f));
                float E = mkv[n] ? 0.f : __expf(__expf(-dist));
                rs[r] += E;
                Es[w][(quad*4 + r)*EPAD + n*16 + q16] = f2b(E);
            }
        }
        // PV: A = own-wave Es (same-wave write->read, lgkmcnt ordered)
        s8v af = *(const s8v*)(&Es[w][q16*EPAD + quad*8]);
        #pragma unroll
        for (int n = 0; n < 16; ++n) {
            s8v vb = *(const s8v*)(Vs[cur] + (n*16 + q16)*32 +
                                   ((quad ^ ((q16 >> 1) & 3))*8));
            O[n] = __builtin_amdgcn_mfma_f32_16x16x32_bf16(af, vb, O[n], 0, 0, 0);
        }
        // stream E tile (row-major, bf16) to global for the normalize pass
        *(s8v*)(ebase + k0) = *(const s8v*)esrc;
    }

    // rowsum (complete: block covered all k); butterfly leaves sum in all lanes
    float inv[4];
    #pragma unroll
    for (int r = 0; r < 4; ++r) {
        float v = rs[r];
        v += __shfl_xor(v, 1, 16);
        v += __shfl_xor(v, 2, 16);
        v += __shfl_xor(v, 4, 16);
        v += __shfl_xor(v, 8, 16);
        if (q16 == 0) rowsum[qrow + quad*4 + r] = v;
        inv[r] = 1.0f / v;
    }

    #pragma unroll
    for (int n = 0; n < 16; ++n)
        #pragma unroll
        for (int r = 0; r < 4; ++r)
            att_out[(size_t)(qrow + quad*4 + r)*D_ + n*16 + q16] = O[n][r] * inv[r];
}

// -------- K3: attn = E * (1/rowsum), pure elementwise, HBM-bound --------
// grid = NROW blocks (one q-row each), block 256; thread handles 8 k.
__global__ __launch_bounds__(256) void norm_kernel(
    const unsigned short* __restrict__ Eb,
    const float* __restrict__ rowsum,
    float* __restrict__ attn_out)
{
    const int row = blockIdx.x;
    const int t   = threadIdx.x;
    const float inv = 1.0f / rowsum[row];
    const size_t base = (size_t)row * L_ + t*8;

    s8v e = *(const s8v*)(Eb + base);
    float4 o0, o1;
    o0.x = __builtin_bit_cast(float, ((unsigned)(unsigned short)e[0]) << 16) * inv;
    o0.y = __builtin_bit_cast(float, ((unsigned)(unsigned short)e[1]) << 16) * inv;
    o0.z = __builtin_bit_cast(float, ((unsigned)(unsigned short)e[2]) << 16) * inv;
    o0.w = __builtin_bit_cast(float, ((unsigned)(unsigned short)e[3]) << 16) * inv;
    o1.x = __builtin_bit_cast(float, ((unsigned)(unsigned short)e[4]) << 16) * inv;
    o1.y = __builtin_bit_cast(float, ((unsigned)(unsigned short)e[5]) << 16) * inv;
    o1.z = __builtin_bit_cast(float, ((unsigned)(unsigned short)e[6]) << 16) * inv;
    o1.w = __builtin_bit_cast(float, ((unsigned)(unsigned short)e[7]) << 16) * inv;
    *(float4*)(attn_out + base)     = o0;
    *(float4*)(attn_out + base + 4) = o1;
}

extern "C" void kernel_launch(void* const* d_in, const int* in_sizes, int n_in,
                              void* d_out, int out_size, void* d_ws, size_t ws_size,
                              hipStream_t stream) {
    (void)in_sizes; (void)n_in; (void)out_size; (void)ws_size;
    const float* x  = (const float*)d_in[0];
    const float* y  = (const float*)d_in[1];
    const unsigned char* mask = (const unsigned char*)d_in[2];
    const float* Wq = (const float*)d_in[3];
    const float* Wk = (const float*)d_in[4];
    const float* Wv = (const float*)d_in[5];

    // ws: Qb | Kb | Vt (bf16) | qn | kn | rowsum (fp32) | Eb (bf16, 134 MB)
    char* ws = (char*)d_ws;
    unsigned short* Qb = (unsigned short*)ws;
    unsigned short* Kb = Qb + (size_t)NROW * D_;
    unsigned short* Vt = Kb + (size_t)NROW * D_;
    float* qn     = (float*)(ws + 3 * (size_t)NROW * D_ * 2);
    float* kn     = qn + NROW;
    float* rowsum = kn + NROW;
    unsigned short* Eb = (unsigned short*)(rowsum + NROW);

    float* att_out = (float*)d_out;                       // [B, LQ, D]
    float* attn    = att_out + (size_t)NROW * D_;         // [B, LQ, LK]

    qkv_kernel<<<dim3(512, 2), 256, 0, stream>>>(x, y, Wq, Wk, Wv,
                                                 Qb, Kb, Vt, qn, kn);
    attnpv_kernel<<<dim3(32, 16), 256, 0, stream>>>(Qb, Kb, Vt, qn, kn, mask,
                                                    Eb, rowsum, att_out);
    norm_kernel<<<dim3(NROW), 256, 0, stream>>>(Eb, rowsum, attn);
}